// Round 16
// baseline (95.848 us; speedup 1.0000x reference)
//
#include <hip/hip_runtime.h>
#include <hip/hip_bf16.h>
#include <math.h>
#include <cstdint>
#include <cstddef>

typedef __bf16 bf16x8 __attribute__((ext_vector_type(8)));
typedef __bf16 bf16x4 __attribute__((ext_vector_type(4)));
typedef short  s16x4  __attribute__((ext_vector_type(4)));
typedef float  f32x4  __attribute__((ext_vector_type(4)));

#define GLOAD16(g, l) __builtin_amdgcn_global_load_lds( \
    (const __attribute__((address_space(1))) void*)(g),  \
    (__attribute__((address_space(3))) void*)(l), 16, 0, 0)

__device__ __forceinline__ unsigned short f2bf(float f) {
    union { float f; unsigned u; } v; v.f = f;
    unsigned u = v.u;
    u += 0x7fffu + ((u >> 16) & 1u);          // round-to-nearest-even
    return (unsigned short)(u >> 16);
}

__device__ __forceinline__ unsigned pack_bf16x2(float a, float b) {
    __hip_bfloat162 h = __float22bfloat162_rn(make_float2(a, b));
    return *reinterpret_cast<unsigned*>(&h);   // v_cvt_pk_bf16_f32
}

// 16x16x16 bf16 MFMA (2-VGPR A/B operands, kv as k-dim)
__device__ __forceinline__ f32x4 mfma16(bf16x4 a, bf16x4 b, f32x4 c) {
#if __has_builtin(__builtin_amdgcn_mfma_f32_16x16x16_bf16)
    return __builtin_amdgcn_mfma_f32_16x16x16_bf16(a, b, c, 0, 0, 0);
#elif __has_builtin(__builtin_amdgcn_mfma_f32_16x16x16bf16_1k)
    return __builtin_amdgcn_mfma_f32_16x16x16bf16_1k(
        __builtin_bit_cast(s16x4, a), __builtin_bit_cast(s16x4, b), c, 0, 0, 0);
#else
    asm volatile("v_mfma_f32_16x16x16_bf16 %0, %1, %2, %0"
                 : "+v"(c) : "v"(a), "v"(b));
    return c;
#endif
}

// ---- fused fp32 -> bf16 converts (x | qkv_w [Q rows pre-scaled] | proj_w) ----
__global__ __launch_bounds__(256) void cvt_all(
    const float* __restrict__ x,
    const float* __restrict__ qkvw,
    const float* __restrict__ projw,
    unsigned short* __restrict__ xb,
    unsigned short* __restrict__ wqkv,
    unsigned short* __restrict__ wproj)
{
    const int N1 = 4096 * 768;          // x
    const int N2 = 2304 * 768;          // qkv_w
    const int SC = 768 * 768;           // Q rows of qkv_w (scaled)
    const float C2 = 0.18033688011112042f;   // 0.125 * log2(e)
    int i = ((int)blockIdx.x * 256 + (int)threadIdx.x) * 4;

    const float* src;
    unsigned short* dst;
    int j;
    bool sc = false;
    if (i < N1)           { src = x;     dst = xb;    j = i; }
    else if (i < N1 + N2) { j = i - N1;  src = qkvw;  dst = wqkv;  sc = (j < SC); }
    else                  { j = i - N1 - N2; src = projw; dst = wproj; }

    float4 v = *reinterpret_cast<const float4*>(src + j);
    if (sc) { v.x *= C2; v.y *= C2; v.z *= C2; v.w *= C2; }
    uint2 pk;
    pk.x = pack_bf16x2(v.x, v.y);
    pk.y = pack_bf16x2(v.z, v.w);
    *reinterpret_cast<uint2*>(dst + j) = pk;
}

// ---- bf16 GEMM, C = A * B^T: 3-deep LDS, BK=32, counted vmcnt pipeline ----
// (R15 verbatim — benched: non-attn 44.4 -> 41.8 us)
template <int MODE, int MROWS, int NF>
__global__ __launch_bounds__(256) void gemm_bt(
    const unsigned short* __restrict__ A,
    const unsigned short* __restrict__ B,
    unsigned short* __restrict__ Cb,
    unsigned short* __restrict__ Vt,
    float* __restrict__ Cf,
    const float* __restrict__ bias,
    int M, int N, int K)
{
    constexpr int MI = MROWS / 32;
    constexpr int AC = MROWS / 64;       // A gloads per wave per stage
    constexpr int BC = NF / 2;           // B gloads per wave per stage
    constexpr int NL = AC + BC;          // loads per wave per stage
    __shared__ __align__(16) unsigned short Al[3][MROWS * 32];
    __shared__ __align__(16) unsigned short Bl[3][NF * 32 * 32];
    const int bm   = blockIdx.x * MROWS;
    const int bn   = blockIdx.y * (NF * 32);
    const int tid  = (int)threadIdx.x;
    const int wave = tid >> 6;
    const int lane = tid & 63;
    const int wr   = wave >> 1;
    const int wc   = wave & 1;
    const int q    = lane & 15;
    const int g    = lane >> 4;
    const int g4   = g * 4;
    const int rswz = (g ^ ((q >> 1) & 3)) << 3;   // physical slot offset (elems)

    f32x4 acc[MI][NF] = {};

    const int srow = lane >> 2;                               // row in 16-row chunk
    const int scol = ((lane & 3) ^ ((lane >> 3) & 3)) << 3;   // src col (elems)

    auto stage = [&](int buf, int k0) {
#pragma unroll
        for (int i = 0; i < AC; ++i) {
            const int chunk = wave * AC + i;
            GLOAD16(A + (size_t)(bm + chunk * 16 + srow) * K + (k0 + scol),
                    &Al[buf][chunk * 512]);
        }
#pragma unroll
        for (int i = 0; i < BC; ++i) {
            const int chunk = wave * BC + i;
            GLOAD16(B + (size_t)(bn + chunk * 16 + srow) * K + (k0 + scol),
                    &Bl[buf][chunk * 512]);
        }
    };

    stage(0, 0);
    stage(1, 32);

    const int nt = K / 32;               // 24
    for (int t = 0; t < nt; ++t) {
        const int cur = t % 3;
        // tile t resident (own loads) + cross-wave visibility via barrier
        if (t < nt - 1) {
            if constexpr (NL == 4)
                asm volatile("s_waitcnt vmcnt(4)\n\ts_barrier" ::: "memory");
            else
                asm volatile("s_waitcnt vmcnt(2)\n\ts_barrier" ::: "memory");
        } else {
            asm volatile("s_waitcnt vmcnt(0)\n\ts_barrier" ::: "memory");
        }
        if (t + 2 < nt) stage((cur + 2) % 3, (t + 2) * 32);

        bf16x8 af[MI], bf[NF];
#pragma unroll
        for (int mi = 0; mi < MI; ++mi)
            af[mi] = *(const bf16x8*)&Al[cur][(wr * (MROWS / 2) + mi * 16 + q) * 32 + rswz];
#pragma unroll
        for (int ni = 0; ni < NF; ++ni)
            bf[ni] = *(const bf16x8*)&Bl[cur][(wc * 16 * NF + ni * 16 + q) * 32 + rswz];
#pragma unroll
        for (int mi = 0; mi < MI; ++mi)
#pragma unroll
            for (int ni = 0; ni < NF; ++ni)
                acc[mi][ni] = __builtin_amdgcn_mfma_f32_16x16x32_bf16(
                    af[mi], bf[ni], acc[mi][ni], 0, 0, 0);
    }

#pragma unroll
    for (int mi = 0; mi < MI; ++mi) {
        const int row0 = bm + wr * (MROWS / 2) + mi * 16 + g4;
        if constexpr (MODE == 1) {
#pragma unroll
            for (int ni = 0; ni < NF; ++ni) {
                const int col = bn + wc * 16 * NF + ni * 16 + q;
#pragma unroll
                for (int r = 0; r < 4; ++r)
                    Cf[(size_t)(row0 + r) * N + col] = acc[mi][ni][r] + bias[col];
            }
        } else {
            if (bn < 1536) {
#pragma unroll
                for (int ni = 0; ni < NF; ++ni) {
                    const int col = bn + wc * 16 * NF + ni * 16 + q;
#pragma unroll
                    for (int r = 0; r < 4; ++r)
                        Cb[(size_t)(row0 + r) * 1536 + col] = f2bf(acc[mi][ni][r]);
                }
            } else {
                const int bb  = row0 >> 11;
                const int np  = row0 & 2047;           // np % 4 == 0
                const int tt  = np >> 6;
                const int wv  = (np >> 4) & 3;
                const int gg  = (np >> 2) & 3;
#pragma unroll
                for (int ni = 0; ni < NF; ++ni) {
                    const int vcol = bn + wc * 16 * NF + ni * 16 + q - 1536;
                    const int hv = vcol >> 6, d = vcol & 63;
                    const size_t idx =
                        ((size_t)((bb * 12 + hv) * 32 + tt) * 4 + wv) * 1024
                        + gg * 256 + d * 4;
                    uint2 w;
                    w.x = pack_bf16x2(acc[mi][ni][0], acc[mi][ni][1]);
                    w.y = pack_bf16x2(acc[mi][ni][2], acc[mi][ni][3]);
                    *reinterpret_cast<uint2*>(&Vt[idx]) = w;   // coalesced
                }
            }
        }
    }
}

// --- fused flash attention: kv-split waves, 32-q blocks (4 blocks/CU) ------
// R12 loop structure; q-tile halved 64->32 so grid 1536 lifts occupancy past
// the old 3-blocks/CU grid cap (LDS-capped at 4/CU now).
// qk: [B*N][1536] bf16 (Q pre-scaled); vT tiled [bhh][t][w][g][d][j]
// 1D grid 1536, XCD-chunked: xcd = bid&7 owns bh in {3*xcd..3*xcd+2}.
__global__ __launch_bounds__(256, 4) void attn_fwd(
    const unsigned short* __restrict__ qk,
    const unsigned short* __restrict__ vT,
    const int* __restrict__ mask,
    unsigned short* __restrict__ out)
{
    const int NN = 2048, H = 12;
    const int bid = (int)blockIdx.x;
    const int bhh = (bid & 7) * 3 + ((bid >> 3) >> 6);   // 0..23
    const int qt  = (bid >> 3) & 63;
    const int b   = bhh / H, h = bhh % H;
    const int q0  = qt * 32;
    const int tid = (int)threadIdx.x, wave = tid >> 6, lane = tid & 63;
    const int g   = lane >> 4;
    const int q   = lane & 15;
    const int swz = (q & 7) << 3;

    // LDS: K 2x4096 | V 2x4096 | lbuf 128 f32  => 33280 B
    __shared__ __align__(16) unsigned short LDS[16640];
    unsigned short* Kl0 = LDS;           // [buf][kv 64][d 64]
    unsigned short* Vl0 = LDS + 8192;    // [buf][wave][g 4][d 64][j 4]

    // wave-local mask vote: all 2048 entries nonzero?
    bool allone;
    {
        const int* mrow = mask + b * NN + lane * 32;
        unsigned mv = 0xFFFFFFFFu;
#pragma unroll
        for (int i = 0; i < 8; ++i) {
            int4 m = *reinterpret_cast<const int4*>(mrow + i * 4);
            mv = min(mv, min(min((unsigned)m.x, (unsigned)m.y),
                             min((unsigned)m.z, (unsigned)m.w)));
        }
        allone = __all(mv != 0u);
    }

    // Q B-fragments for 2 q-tiles: B[k=d=kk*32+g*8+j][col=q0+16qt+q]
    bf16x8 qf[2][2];
#pragma unroll
    for (int kk = 0; kk < 2; ++kk)
#pragma unroll
        for (int qtl = 0; qtl < 2; ++qtl)
            qf[kk][qtl] = *reinterpret_cast<const bf16x8*>(
                &qk[(size_t)(b * NN + q0 + 16 * qtl + q) * 1536 + h * 64 + kk * 32 + g * 8]);

    // K staging (own 16 kv rows; linear LDS dest, inverse-swizzled source col)
    const char* kg0 = (const char*)(qk + (size_t)(b * NN + wave * 16 + (lane >> 3)) * 1536
                                    + 768 + h * 64 + ((lane & 7) ^ (lane >> 3)) * 8);
    const char* kg1 = kg0 + (size_t)8 * 1536 * 2;
    // V staging: vT tiled layout — perfectly linear, lane*16B
    const unsigned short* vgp = vT + ((size_t)bhh * 32 * 4 + wave) * 1024 + lane * 8;

    auto stageK = [&](int buf) {
        GLOAD16(kg0, &Kl0[buf * 4096 + wave * 1024]);
        GLOAD16(kg1, &Kl0[buf * 4096 + wave * 1024 + 512]);
        kg0 += (size_t)64 * 1536 * 2;
        kg1 += (size_t)64 * 1536 * 2;
    };
    auto stageV = [&](int buf) {
        GLOAD16(vgp,       &Vl0[buf * 4096 + wave * 1024]);
        GLOAD16(vgp + 512, &Vl0[buf * 4096 + wave * 1024 + 512]);
        vgp += 4096;                     // next kv tile
    };

    f32x4 oacc[4][2] = {};          // [ct: d-tile][qtl: q-tile]
    float l[2] = {0.f, 0.f};

    stageK(0); stageV(0);           // 4 loads in flight (no barrier needed)

    int cur = 0;
    for (int it = 0; it < 32; ++it) {
        if (it < 31) { stageK(cur ^ 1); stageV(cur ^ 1); }

        // K(it) resident; V(it) + next iter's 4 stay in flight
        if (it < 31) asm volatile("s_waitcnt vmcnt(6)" ::: "memory");
        else         asm volatile("s_waitcnt vmcnt(2)" ::: "memory");

        // S^T[own 16 kv][32 q] = K_own * Q^T  (exp2 units; scale pre-folded)
        f32x4 s[2] = {};
        __builtin_amdgcn_s_setprio(1);
#pragma unroll
        for (int kk = 0; kk < 2; ++kk) {
            bf16x8 kf = *(const bf16x8*)&Kl0[cur * 4096 + (16 * wave + q) * 64
                                             + ((kk * 32 + g * 8) ^ swz)];
#pragma unroll
            for (int qtl = 0; qtl < 2; ++qtl)
                s[qtl] = __builtin_amdgcn_mfma_f32_16x16x32_bf16(kf, qf[kk][qtl], s[qtl], 0, 0, 0);
        }
        __builtin_amdgcn_s_setprio(0);

        if (!allone) {               // cold path: mask by absolute kv
            int4 mr = *reinterpret_cast<const int4*>(
                &mask[b * NN + it * 64 + 16 * wave + 4 * g]);
#pragma unroll
            for (int qtl = 0; qtl < 2; ++qtl) {
                if (mr.x == 0) s[qtl][0] = -INFINITY;
                if (mr.y == 0) s[qtl][1] = -INFINITY;
                if (mr.z == 0) s[qtl][2] = -INFINITY;
                if (mr.w == 0) s[qtl][3] = -INFINITY;
            }
        }

        // p = exp2(s); per-lane l partials (reduced at epilogue); pack to bf16
        bf16x4 pb[2];
#pragma unroll
        for (int qtl = 0; qtl < 2; ++qtl) {
            float p0 = __builtin_amdgcn_exp2f(s[qtl][0]);
            float p1 = __builtin_amdgcn_exp2f(s[qtl][1]);
            float p2 = __builtin_amdgcn_exp2f(s[qtl][2]);
            float p3 = __builtin_amdgcn_exp2f(s[qtl][3]);
            l[qtl] += (p0 + p1) + (p2 + p3);
            uint2 t;
            t.x = pack_bf16x2(p0, p1);
            t.y = pack_bf16x2(p2, p3);
            pb[qtl] = __builtin_bit_cast(bf16x4, t);
        }

        // V(it) resident; next iter's 4 remain in flight
        if (it < 31) asm volatile("s_waitcnt vmcnt(4)" ::: "memory");
        else         asm volatile("s_waitcnt vmcnt(0)" ::: "memory");

        // O^T[64 d][32 q] partial += V_own^T * P^T  (P in registers)
        __builtin_amdgcn_s_setprio(1);
#pragma unroll
        for (int ct = 0; ct < 4; ++ct) {
            // [g][d][j] layout: banks 2q,2q+1 -> conflict-free
            bf16x4 va = *(const bf16x4*)&Vl0[cur * 4096 + wave * 1024
                                             + g * 256 + (16 * ct + q) * 4];
#pragma unroll
            for (int qtl = 0; qtl < 2; ++qtl)
                oacc[ct][qtl] = mfma16(va, pb[qtl], oacc[ct][qtl]);
        }
        __builtin_amdgcn_s_setprio(0);

        cur ^= 1;
    }

    __syncthreads();   // all waves done with K/V LDS before epilogue overlay

    // ---- epilogue: reduce l (over g, then waves) and O (over waves) ----
#pragma unroll
    for (int qtl = 0; qtl < 2; ++qtl) {
        l[qtl] += __shfl_xor(l[qtl], 16);
        l[qtl] += __shfl_xor(l[qtl], 32);
    }
    float* lb = (float*)&LDS[16384];     // 128 f32
    float* fb = (float*)&LDS[0];         // 4096 f32 scratch (K region, 16 KB)
    if (g == 0) {
#pragma unroll
        for (int qtl = 0; qtl < 2; ++qtl) lb[wave * 32 + qtl * 16 + q] = l[qtl];
    }
    // round 1: waves 1,3 dump partials (8 KB each)
    if (wave & 1) {
        float* dst = fb + (wave >> 1) * 2048;
#pragma unroll
        for (int ct = 0; ct < 4; ++ct)
#pragma unroll
            for (int qtl = 0; qtl < 2; ++qtl)
                *reinterpret_cast<f32x4*>(&dst[(ct * 2 + qtl) * 256 + lane * 4]) = oacc[ct][qtl];
    }
    __syncthreads();
    if (!(wave & 1)) {
        float* srcp = fb + (wave >> 1) * 2048;
#pragma unroll
        for (int ct = 0; ct < 4; ++ct)
#pragma unroll
            for (int qtl = 0; qtl < 2; ++qtl)
                oacc[ct][qtl] += *reinterpret_cast<f32x4*>(&srcp[(ct * 2 + qtl) * 256 + lane * 4]);
    }
    __syncthreads();
    // round 2: wave 2 dumps merged partial
    if (wave == 2) {
#pragma unroll
        for (int ct = 0; ct < 4; ++ct)
#pragma unroll
            for (int qtl = 0; qtl < 2; ++qtl)
                *reinterpret_cast<f32x4*>(&fb[(ct * 2 + qtl) * 256 + lane * 4]) = oacc[ct][qtl];
    }
    __syncthreads();
    if (wave == 0) {
        float inv[2];
#pragma unroll
        for (int qtl = 0; qtl < 2; ++qtl)
            inv[qtl] = 1.0f / (lb[qtl * 16 + q] + lb[32 + qtl * 16 + q]
                              + lb[64 + qtl * 16 + q] + lb[96 + qtl * 16 + q]);
#pragma unroll
        for (int ct = 0; ct < 4; ++ct)
#pragma unroll
            for (int qtl = 0; qtl < 2; ++qtl) {
                f32x4 o = oacc[ct][qtl]
                        + *reinterpret_cast<f32x4*>(&fb[(ct * 2 + qtl) * 256 + lane * 4]);
                uint2 ow;
                ow.x = pack_bf16x2(o[0] * inv[qtl], o[1] * inv[qtl]);
                ow.y = pack_bf16x2(o[2] * inv[qtl], o[3] * inv[qtl]);
                *reinterpret_cast<uint2*>(
                    &out[(size_t)(b * NN + q0 + 16 * qtl + q) * 768 + h * 64 + 16 * ct + 4 * g]) = ow;
            }
    }
}

// ---------------- host launch ----------------
extern "C" void kernel_launch(void* const* d_in, const int* in_sizes, int n_in,
                              void* d_out, int out_size, void* d_ws, size_t ws_size,
                              hipStream_t stream)
{
    const float* x      = (const float*)d_in[0];
    const int*   mask   = (const int*)d_in[1];
    const float* qkv_w  = (const float*)d_in[2];
    const float* proj_w = (const float*)d_in[3];
    const float* proj_b = (const float*)d_in[4];
    float* out = (float*)d_out;

    const int BN = 2 * 2048;
    const int C  = 768;
    const int C3 = 2304;

    char* w = (char*)d_ws;
    unsigned short* xb    = (unsigned short*)w; w += (size_t)BN * C    * 2;
    unsigned short* wqkv  = (unsigned short*)w; w += (size_t)C3 * C    * 2;
    unsigned short* wproj = (unsigned short*)w; w += (size_t)C  * C    * 2;
    unsigned short* qk    = (unsigned short*)w; w += (size_t)BN * 1536 * 2;
    unsigned short* vT    = (unsigned short*)w; w += (size_t)24 * 64 * 2048 * 2;
    unsigned short* ao    = (unsigned short*)w;

    // fused converts (Q weight rows pre-scaled by 0.125*log2e)
    {
        const int total = (BN * C + C3 * C + C * C) / 4;
        cvt_all<<<total / 256, 256, 0, stream>>>(x, qkv_w, proj_w, xb, wqkv, wproj);
    }

    // qkv GEMM with split epilogue: Q,K -> qk[.][1536]; V -> vT (tiled layout)
    gemm_bt<2, 128, 4><<<dim3(BN / 128, C3 / 128), 256, 0, stream>>>(
        xb, wqkv, qk, vT, nullptr, nullptr, BN, C3, C);

    attn_fwd<<<dim3(1536), 256, 0, stream>>>(qk, vT, mask, ao);

    // out = ao @ proj_w^T + b (fp32), 64x64 tiles -> 768 blocks (3/CU balanced)
    gemm_bt<1, 64, 2><<<dim3(BN / 64, C / 64), 256, 0, stream>>>(
        ao, wproj, nullptr, nullptr, out, proj_b, BN, C, C);
}

// Round 17
// 93.912 us; speedup vs baseline: 1.0206x; 1.0206x over previous
//
#include <hip/hip_runtime.h>
#include <hip/hip_bf16.h>
#include <math.h>
#include <cstdint>
#include <cstddef>

typedef __bf16 bf16x8 __attribute__((ext_vector_type(8)));
typedef __bf16 bf16x4 __attribute__((ext_vector_type(4)));
typedef short  s16x4  __attribute__((ext_vector_type(4)));
typedef float  f32x4  __attribute__((ext_vector_type(4)));

#define GLOAD16(g, l) __builtin_amdgcn_global_load_lds( \
    (const __attribute__((address_space(1))) void*)(g),  \
    (__attribute__((address_space(3))) void*)(l), 16, 0, 0)

__device__ __forceinline__ unsigned short f2bf(float f) {
    union { float f; unsigned u; } v; v.f = f;
    unsigned u = v.u;
    u += 0x7fffu + ((u >> 16) & 1u);          // round-to-nearest-even
    return (unsigned short)(u >> 16);
}

__device__ __forceinline__ unsigned pack_bf16x2(float a, float b) {
    __hip_bfloat162 h = __float22bfloat162_rn(make_float2(a, b));
    return *reinterpret_cast<unsigned*>(&h);   // v_cvt_pk_bf16_f32
}

// 16x16x16 bf16 MFMA (2-VGPR A/B operands, kv as k-dim)
__device__ __forceinline__ f32x4 mfma16(bf16x4 a, bf16x4 b, f32x4 c) {
#if __has_builtin(__builtin_amdgcn_mfma_f32_16x16x16_bf16)
    return __builtin_amdgcn_mfma_f32_16x16x16_bf16(a, b, c, 0, 0, 0);
#elif __has_builtin(__builtin_amdgcn_mfma_f32_16x16x16bf16_1k)
    return __builtin_amdgcn_mfma_f32_16x16x16bf16_1k(
        __builtin_bit_cast(s16x4, a), __builtin_bit_cast(s16x4, b), c, 0, 0, 0);
#else
    asm volatile("v_mfma_f32_16x16x16_bf16 %0, %1, %2, %0"
                 : "+v"(c) : "v"(a), "v"(b));
    return c;
#endif
}

// ---- fused fp32 -> bf16 converts (x | qkv_w [Q rows pre-scaled] | proj_w) ----
__global__ __launch_bounds__(256) void cvt_all(
    const float* __restrict__ x,
    const float* __restrict__ qkvw,
    const float* __restrict__ projw,
    unsigned short* __restrict__ xb,
    unsigned short* __restrict__ wqkv,
    unsigned short* __restrict__ wproj)
{
    const int N1 = 4096 * 768;          // x
    const int N2 = 2304 * 768;          // qkv_w
    const int SC = 768 * 768;           // Q rows of qkv_w (scaled)
    const float C2 = 0.18033688011112042f;   // 0.125 * log2(e)
    int i = ((int)blockIdx.x * 256 + (int)threadIdx.x) * 4;

    const float* src;
    unsigned short* dst;
    int j;
    bool sc = false;
    if (i < N1)           { src = x;     dst = xb;    j = i; }
    else if (i < N1 + N2) { j = i - N1;  src = qkvw;  dst = wqkv;  sc = (j < SC); }
    else                  { j = i - N1 - N2; src = projw; dst = wproj; }

    float4 v = *reinterpret_cast<const float4*>(src + j);
    if (sc) { v.x *= C2; v.y *= C2; v.z *= C2; v.w *= C2; }
    uint2 pk;
    pk.x = pack_bf16x2(v.x, v.y);
    pk.y = pack_bf16x2(v.z, v.w);
    *reinterpret_cast<uint2*>(dst + j) = pk;
}

// ---- bf16 GEMM, C = A * B^T: 3-deep LDS, BK=32, counted vmcnt pipeline ----
// (R15 verbatim — benched: non-attn 44.4 -> 41.8 us)
template <int MODE, int MROWS, int NF>
__global__ __launch_bounds__(256) void gemm_bt(
    const unsigned short* __restrict__ A,
    const unsigned short* __restrict__ B,
    unsigned short* __restrict__ Cb,
    unsigned short* __restrict__ Vt,
    float* __restrict__ Cf,
    const float* __restrict__ bias,
    int M, int N, int K)
{
    constexpr int MI = MROWS / 32;
    constexpr int AC = MROWS / 64;       // A gloads per wave per stage
    constexpr int BC = NF / 2;           // B gloads per wave per stage
    constexpr int NL = AC + BC;          // loads per wave per stage
    __shared__ __align__(16) unsigned short Al[3][MROWS * 32];
    __shared__ __align__(16) unsigned short Bl[3][NF * 32 * 32];
    const int bm   = blockIdx.x * MROWS;
    const int bn   = blockIdx.y * (NF * 32);
    const int tid  = (int)threadIdx.x;
    const int wave = tid >> 6;
    const int lane = tid & 63;
    const int wr   = wave >> 1;
    const int wc   = wave & 1;
    const int q    = lane & 15;
    const int g    = lane >> 4;
    const int g4   = g * 4;
    const int rswz = (g ^ ((q >> 1) & 3)) << 3;   // physical slot offset (elems)

    f32x4 acc[MI][NF] = {};

    const int srow = lane >> 2;                               // row in 16-row chunk
    const int scol = ((lane & 3) ^ ((lane >> 3) & 3)) << 3;   // src col (elems)

    auto stage = [&](int buf, int k0) {
#pragma unroll
        for (int i = 0; i < AC; ++i) {
            const int chunk = wave * AC + i;
            GLOAD16(A + (size_t)(bm + chunk * 16 + srow) * K + (k0 + scol),
                    &Al[buf][chunk * 512]);
        }
#pragma unroll
        for (int i = 0; i < BC; ++i) {
            const int chunk = wave * BC + i;
            GLOAD16(B + (size_t)(bn + chunk * 16 + srow) * K + (k0 + scol),
                    &Bl[buf][chunk * 512]);
        }
    };

    stage(0, 0);
    stage(1, 32);

    const int nt = K / 32;               // 24
    for (int t = 0; t < nt; ++t) {
        const int cur = t % 3;
        // tile t resident (own loads) + cross-wave visibility via barrier
        if (t < nt - 1) {
            if constexpr (NL == 4)
                asm volatile("s_waitcnt vmcnt(4)\n\ts_barrier" ::: "memory");
            else
                asm volatile("s_waitcnt vmcnt(2)\n\ts_barrier" ::: "memory");
        } else {
            asm volatile("s_waitcnt vmcnt(0)\n\ts_barrier" ::: "memory");
        }
        if (t + 2 < nt) stage((cur + 2) % 3, (t + 2) * 32);

        bf16x8 af[MI], bf[NF];
#pragma unroll
        for (int mi = 0; mi < MI; ++mi)
            af[mi] = *(const bf16x8*)&Al[cur][(wr * (MROWS / 2) + mi * 16 + q) * 32 + rswz];
#pragma unroll
        for (int ni = 0; ni < NF; ++ni)
            bf[ni] = *(const bf16x8*)&Bl[cur][(wc * 16 * NF + ni * 16 + q) * 32 + rswz];
#pragma unroll
        for (int mi = 0; mi < MI; ++mi)
#pragma unroll
            for (int ni = 0; ni < NF; ++ni)
                acc[mi][ni] = __builtin_amdgcn_mfma_f32_16x16x32_bf16(
                    af[mi], bf[ni], acc[mi][ni], 0, 0, 0);
    }

#pragma unroll
    for (int mi = 0; mi < MI; ++mi) {
        const int row0 = bm + wr * (MROWS / 2) + mi * 16 + g4;
        if constexpr (MODE == 1) {
#pragma unroll
            for (int ni = 0; ni < NF; ++ni) {
                const int col = bn + wc * 16 * NF + ni * 16 + q;
#pragma unroll
                for (int r = 0; r < 4; ++r)
                    Cf[(size_t)(row0 + r) * N + col] = acc[mi][ni][r] + bias[col];
            }
        } else {
            if (bn < 1536) {
#pragma unroll
                for (int ni = 0; ni < NF; ++ni) {
                    const int col = bn + wc * 16 * NF + ni * 16 + q;
#pragma unroll
                    for (int r = 0; r < 4; ++r)
                        Cb[(size_t)(row0 + r) * 1536 + col] = f2bf(acc[mi][ni][r]);
                }
            } else {
                const int bb  = row0 >> 11;
                const int np  = row0 & 2047;           // np % 4 == 0
                const int tt  = np >> 6;
                const int wv  = (np >> 4) & 3;
                const int gg  = (np >> 2) & 3;
#pragma unroll
                for (int ni = 0; ni < NF; ++ni) {
                    const int vcol = bn + wc * 16 * NF + ni * 16 + q - 1536;
                    const int hv = vcol >> 6, d = vcol & 63;
                    const size_t idx =
                        ((size_t)((bb * 12 + hv) * 32 + tt) * 4 + wv) * 1024
                        + gg * 256 + d * 4;
                    uint2 w;
                    w.x = pack_bf16x2(acc[mi][ni][0], acc[mi][ni][1]);
                    w.y = pack_bf16x2(acc[mi][ni][2], acc[mi][ni][3]);
                    *reinterpret_cast<uint2*>(&Vt[idx]) = w;   // coalesced
                }
            }
        }
    }
}

// --- fused flash attention: kv-split waves, wave-private LDS, 0 barriers ---
// R12 structure (benched 49.7-49.9 us) with the kv loop unrolled 2x so the
// LDS buffer index is compile-time (immediate offsets; less addressing VALU).
// qk: [B*N][1536] bf16 (Q pre-scaled); vT tiled [bhh][t][w][g][d][j]
// 1D grid 768, XCD-chunked: xcd = bid&7 owns bh in {3*xcd..3*xcd+2}.
__global__ __launch_bounds__(256, 3) void attn_fwd(
    const unsigned short* __restrict__ qk,
    const unsigned short* __restrict__ vT,
    const int* __restrict__ mask,
    unsigned short* __restrict__ out)
{
    const int NN = 2048, H = 12;
    const int bid = (int)blockIdx.x;
    const int bhh = (bid & 7) * 3 + ((bid >> 3) >> 5);   // 0..23
    const int qt  = (bid >> 3) & 31;
    const int b   = bhh / H, h = bhh % H;
    const int q0  = qt * 64;
    const int tid = (int)threadIdx.x, wave = tid >> 6, lane = tid & 63;
    const int g   = lane >> 4;
    const int q   = lane & 15;
    const int swz = (q & 7) << 3;

    // LDS: K 2x4096 | V 2x4096 | lbuf 256 f32  => 33792 B
    __shared__ __align__(16) unsigned short LDS[16896];
    unsigned short* Kl0 = LDS;           // [buf][kv 64][d 64]
    unsigned short* Vl0 = LDS + 8192;    // [buf][wave][g 4][d 64][j 4]

    // wave-local mask vote: all 2048 entries nonzero?
    bool allone;
    {
        const int* mrow = mask + b * NN + lane * 32;
        unsigned mv = 0xFFFFFFFFu;
#pragma unroll
        for (int i = 0; i < 8; ++i) {
            int4 m = *reinterpret_cast<const int4*>(mrow + i * 4);
            mv = min(mv, min(min((unsigned)m.x, (unsigned)m.y),
                             min((unsigned)m.z, (unsigned)m.w)));
        }
        allone = __all(mv != 0u);
    }

    // Q B-fragments for all 4 q-tiles: B[k=d=kk*32+g*8+j][col=q0+16qt+q]
    bf16x8 qf[2][4];
#pragma unroll
    for (int kk = 0; kk < 2; ++kk)
#pragma unroll
        for (int qtl = 0; qtl < 4; ++qtl)
            qf[kk][qtl] = *reinterpret_cast<const bf16x8*>(
                &qk[(size_t)(b * NN + q0 + 16 * qtl + q) * 1536 + h * 64 + kk * 32 + g * 8]);

    // K staging (own 16 kv rows; linear LDS dest, inverse-swizzled source col)
    const char* kg0 = (const char*)(qk + (size_t)(b * NN + wave * 16 + (lane >> 3)) * 1536
                                    + 768 + h * 64 + ((lane & 7) ^ (lane >> 3)) * 8);
    const char* kg1 = kg0 + (size_t)8 * 1536 * 2;
    // V staging: vT tiled layout — perfectly linear, lane*16B
    const unsigned short* vgp = vT + ((size_t)bhh * 32 * 4 + wave) * 1024 + lane * 8;

    auto stageK = [&](int buf) {
        GLOAD16(kg0, &Kl0[buf * 4096 + wave * 1024]);
        GLOAD16(kg1, &Kl0[buf * 4096 + wave * 1024 + 512]);
        kg0 += (size_t)64 * 1536 * 2;
        kg1 += (size_t)64 * 1536 * 2;
    };
    auto stageV = [&](int buf) {
        GLOAD16(vgp,       &Vl0[buf * 4096 + wave * 1024]);
        GLOAD16(vgp + 512, &Vl0[buf * 4096 + wave * 1024 + 512]);
        vgp += 4096;                     // next kv tile
    };

    f32x4 oacc[4][4] = {};          // [ct: d-tile][qtl: q-tile]
    float l[4] = {0.f, 0.f, 0.f, 0.f};

    stageK(0); stageV(0);           // 4 loads in flight (no barrier needed)

    // one kv iteration; CUR is a literal at every call site -> LDS offsets fold
    auto body = [&](int CUR, int it) {
        if (it < 31) { stageK(CUR ^ 1); stageV(CUR ^ 1); }

        // K(it) resident; V(it) + next iter's 4 stay in flight
        if (it < 31) asm volatile("s_waitcnt vmcnt(6)" ::: "memory");
        else         asm volatile("s_waitcnt vmcnt(2)" ::: "memory");

        // S^T[own 16 kv][64 q] = K_own * Q^T  (exp2 units; scale pre-folded)
        f32x4 s[4] = {};
        __builtin_amdgcn_s_setprio(1);
#pragma unroll
        for (int kk = 0; kk < 2; ++kk) {
            bf16x8 kf = *(const bf16x8*)&Kl0[CUR * 4096 + (16 * wave + q) * 64
                                             + ((kk * 32 + g * 8) ^ swz)];
#pragma unroll
            for (int qtl = 0; qtl < 4; ++qtl)
                s[qtl] = __builtin_amdgcn_mfma_f32_16x16x32_bf16(kf, qf[kk][qtl], s[qtl], 0, 0, 0);
        }
        __builtin_amdgcn_s_setprio(0);

        if (!allone) {               // cold path: mask by absolute kv
            int4 mr = *reinterpret_cast<const int4*>(
                &mask[b * NN + it * 64 + 16 * wave + 4 * g]);
#pragma unroll
            for (int qtl = 0; qtl < 4; ++qtl) {
                if (mr.x == 0) s[qtl][0] = -INFINITY;
                if (mr.y == 0) s[qtl][1] = -INFINITY;
                if (mr.z == 0) s[qtl][2] = -INFINITY;
                if (mr.w == 0) s[qtl][3] = -INFINITY;
            }
        }

        // p = exp2(s); per-lane l partials (reduced at epilogue); pack to bf16
        bf16x4 pb[4];
#pragma unroll
        for (int qtl = 0; qtl < 4; ++qtl) {
            float p0 = __builtin_amdgcn_exp2f(s[qtl][0]);
            float p1 = __builtin_amdgcn_exp2f(s[qtl][1]);
            float p2 = __builtin_amdgcn_exp2f(s[qtl][2]);
            float p3 = __builtin_amdgcn_exp2f(s[qtl][3]);
            l[qtl] += (p0 + p1) + (p2 + p3);
            uint2 t;
            t.x = pack_bf16x2(p0, p1);
            t.y = pack_bf16x2(p2, p3);
            pb[qtl] = __builtin_bit_cast(bf16x4, t);
        }

        // V(it) resident; next iter's 4 remain in flight
        if (it < 31) asm volatile("s_waitcnt vmcnt(4)" ::: "memory");
        else         asm volatile("s_waitcnt vmcnt(0)" ::: "memory");

        // O^T[64 d][64 q] partial += V_own^T * P^T  (P in registers)
        __builtin_amdgcn_s_setprio(1);
#pragma unroll
        for (int ct = 0; ct < 4; ++ct) {
            // [g][d][j] layout: banks 2q,2q+1 -> conflict-free
            bf16x4 va = *(const bf16x4*)&Vl0[CUR * 4096 + wave * 1024
                                             + g * 256 + (16 * ct + q) * 4];
#pragma unroll
            for (int qtl = 0; qtl < 4; ++qtl)
                oacc[ct][qtl] = mfma16(va, pb[qtl], oacc[ct][qtl]);
        }
        __builtin_amdgcn_s_setprio(0);
    };

#pragma unroll 1
    for (int it2 = 0; it2 < 16; ++it2) {
        body(0, 2 * it2);
        body(1, 2 * it2 + 1);
    }

    __syncthreads();   // all waves done with K/V LDS before epilogue overlay

    // ---- epilogue: reduce l (over g, then waves) and O (over waves) ----
#pragma unroll
    for (int qtl = 0; qtl < 4; ++qtl) {
        l[qtl] += __shfl_xor(l[qtl], 16);
        l[qtl] += __shfl_xor(l[qtl], 32);
    }
    float* lb = (float*)&LDS[16384];
    float* fb = (float*)&LDS[0];
    if (g == 0) {
#pragma unroll
        for (int qtl = 0; qtl < 4; ++qtl) lb[wave * 64 + qtl * 16 + q] = l[qtl];
    }
    // round 1: waves 1,3 dump partials (16 KB each)
    if (wave & 1) {
        float* dst = fb + (wave >> 1) * 4096;
#pragma unroll
        for (int ct = 0; ct < 4; ++ct)
#pragma unroll
            for (int qtl = 0; qtl < 4; ++qtl)
                *reinterpret_cast<f32x4*>(&dst[(ct * 4 + qtl) * 256 + lane * 4]) = oacc[ct][qtl];
    }
    __syncthreads();
    if (!(wave & 1)) {
        float* srcp = fb + (wave >> 1) * 4096;
#pragma unroll
        for (int ct = 0; ct < 4; ++ct)
#pragma unroll
            for (int qtl = 0; qtl < 4; ++qtl)
                oacc[ct][qtl] += *reinterpret_cast<f32x4*>(&srcp[(ct * 4 + qtl) * 256 + lane * 4]);
    }
    __syncthreads();
    // round 2: wave 2 dumps merged partial
    if (wave == 2) {
#pragma unroll
        for (int ct = 0; ct < 4; ++ct)
#pragma unroll
            for (int qtl = 0; qtl < 4; ++qtl)
                *reinterpret_cast<f32x4*>(&fb[(ct * 4 + qtl) * 256 + lane * 4]) = oacc[ct][qtl];
    }
    __syncthreads();
    if (wave == 0) {
        float inv[4];
#pragma unroll
        for (int qtl = 0; qtl < 4; ++qtl)
            inv[qtl] = 1.0f / (lb[qtl * 16 + q] + lb[64 + qtl * 16 + q]
                              + lb[128 + qtl * 16 + q] + lb[192 + qtl * 16 + q]);
#pragma unroll
        for (int ct = 0; ct < 4; ++ct)
#pragma unroll
            for (int qtl = 0; qtl < 4; ++qtl) {
                f32x4 o = oacc[ct][qtl]
                        + *reinterpret_cast<f32x4*>(&fb[(ct * 4 + qtl) * 256 + lane * 4]);
                uint2 ow;
                ow.x = pack_bf16x2(o[0] * inv[qtl], o[1] * inv[qtl]);
                ow.y = pack_bf16x2(o[2] * inv[qtl], o[3] * inv[qtl]);
                *reinterpret_cast<uint2*>(
                    &out[(size_t)(b * NN + q0 + 16 * qtl + q) * 768 + h * 64 + 16 * ct + 4 * g]) = ow;
            }
    }
}

// ---------------- host launch ----------------
extern "C" void kernel_launch(void* const* d_in, const int* in_sizes, int n_in,
                              void* d_out, int out_size, void* d_ws, size_t ws_size,
                              hipStream_t stream)
{
    const float* x      = (const float*)d_in[0];
    const int*   mask   = (const int*)d_in[1];
    const float* qkv_w  = (const float*)d_in[2];
    const float* proj_w = (const float*)d_in[3];
    const float* proj_b = (const float*)d_in[4];
    float* out = (float*)d_out;

    const int BN = 2 * 2048;
    const int C  = 768;
    const int C3 = 2304;

    char* w = (char*)d_ws;
    unsigned short* xb    = (unsigned short*)w; w += (size_t)BN * C    * 2;
    unsigned short* wqkv  = (unsigned short*)w; w += (size_t)C3 * C    * 2;
    unsigned short* wproj = (unsigned short*)w; w += (size_t)C  * C    * 2;
    unsigned short* qk    = (unsigned short*)w; w += (size_t)BN * 1536 * 2;
    unsigned short* vT    = (unsigned short*)w; w += (size_t)24 * 64 * 2048 * 2;
    unsigned short* ao    = (unsigned short*)w;

    // fused converts (Q weight rows pre-scaled by 0.125*log2e)
    {
        const int total = (BN * C + C3 * C + C * C) / 4;
        cvt_all<<<total / 256, 256, 0, stream>>>(x, qkv_w, proj_w, xb, wqkv, wproj);
    }

    // qkv GEMM with split epilogue: Q,K -> qk[.][1536]; V -> vT (tiled layout)
    gemm_bt<2, 128, 4><<<dim3(BN / 128, C3 / 128), 256, 0, stream>>>(
        xb, wqkv, qk, vT, nullptr, nullptr, BN, C3, C);

    attn_fwd<<<dim3(768), 256, 0, stream>>>(qk, vT, mask, ao);

    // out = ao @ proj_w^T + b (fp32), 64x64 tiles -> 768 blocks (3/CU balanced)
    gemm_bt<1, 64, 2><<<dim3(BN / 64, C / 64), 256, 0, stream>>>(
        ao, wproj, nullptr, nullptr, out, proj_b, BN, C, C);
}

// Round 18
// 91.764 us; speedup vs baseline: 1.0445x; 1.0234x over previous
//
#include <hip/hip_runtime.h>
#include <hip/hip_bf16.h>
#include <math.h>
#include <cstdint>
#include <cstddef>

typedef __bf16 bf16x8 __attribute__((ext_vector_type(8)));
typedef __bf16 bf16x4 __attribute__((ext_vector_type(4)));
typedef short  s16x4  __attribute__((ext_vector_type(4)));
typedef float  f32x4  __attribute__((ext_vector_type(4)));

#define GLOAD16(g, l) __builtin_amdgcn_global_load_lds( \
    (const __attribute__((address_space(1))) void*)(g),  \
    (__attribute__((address_space(3))) void*)(l), 16, 0, 0)

__device__ __forceinline__ unsigned short f2bf(float f) {
    union { float f; unsigned u; } v; v.f = f;
    unsigned u = v.u;
    u += 0x7fffu + ((u >> 16) & 1u);          // round-to-nearest-even
    return (unsigned short)(u >> 16);
}

__device__ __forceinline__ unsigned pack_bf16x2(float a, float b) {
    __hip_bfloat162 h = __float22bfloat162_rn(make_float2(a, b));
    return *reinterpret_cast<unsigned*>(&h);   // v_cvt_pk_bf16_f32
}

// 16x16x16 bf16 MFMA (2-VGPR A/B operands, kv as k-dim)
__device__ __forceinline__ f32x4 mfma16(bf16x4 a, bf16x4 b, f32x4 c) {
#if __has_builtin(__builtin_amdgcn_mfma_f32_16x16x16_bf16)
    return __builtin_amdgcn_mfma_f32_16x16x16_bf16(a, b, c, 0, 0, 0);
#elif __has_builtin(__builtin_amdgcn_mfma_f32_16x16x16bf16_1k)
    return __builtin_amdgcn_mfma_f32_16x16x16bf16_1k(
        __builtin_bit_cast(s16x4, a), __builtin_bit_cast(s16x4, b), c, 0, 0, 0);
#else
    asm volatile("v_mfma_f32_16x16x16_bf16 %0, %1, %2, %0"
                 : "+v"(c) : "v"(a), "v"(b));
    return c;
#endif
}

// ---- fused fp32 -> bf16 converts (x | qkv_w [Q rows pre-scaled] | proj_w) ----
__global__ __launch_bounds__(256) void cvt_all(
    const float* __restrict__ x,
    const float* __restrict__ qkvw,
    const float* __restrict__ projw,
    unsigned short* __restrict__ xb,
    unsigned short* __restrict__ wqkv,
    unsigned short* __restrict__ wproj)
{
    const int N1 = 4096 * 768;          // x
    const int N2 = 2304 * 768;          // qkv_w
    const int SC = 768 * 768;           // Q rows of qkv_w (scaled)
    const float C2 = 0.18033688011112042f;   // 0.125 * log2(e)
    int i = ((int)blockIdx.x * 256 + (int)threadIdx.x) * 4;

    const float* src;
    unsigned short* dst;
    int j;
    bool sc = false;
    if (i < N1)           { src = x;     dst = xb;    j = i; }
    else if (i < N1 + N2) { j = i - N1;  src = qkvw;  dst = wqkv;  sc = (j < SC); }
    else                  { j = i - N1 - N2; src = projw; dst = wproj; }

    float4 v = *reinterpret_cast<const float4*>(src + j);
    if (sc) { v.x *= C2; v.y *= C2; v.z *= C2; v.w *= C2; }
    uint2 pk;
    pk.x = pack_bf16x2(v.x, v.y);
    pk.y = pack_bf16x2(v.z, v.w);
    *reinterpret_cast<uint2*>(dst + j) = pk;
}

// ---- bf16 GEMM, C = A * B^T: 3-deep LDS, BK=32, counted vmcnt pipeline ----
// (R15 verbatim — benched: non-attn 44.4 -> 41.8 us)
template <int MODE, int MROWS, int NF>
__global__ __launch_bounds__(256) void gemm_bt(
    const unsigned short* __restrict__ A,
    const unsigned short* __restrict__ B,
    unsigned short* __restrict__ Cb,
    unsigned short* __restrict__ Vt,
    float* __restrict__ Cf,
    const float* __restrict__ bias,
    int M, int N, int K)
{
    constexpr int MI = MROWS / 32;
    constexpr int AC = MROWS / 64;       // A gloads per wave per stage
    constexpr int BC = NF / 2;           // B gloads per wave per stage
    constexpr int NL = AC + BC;          // loads per wave per stage
    __shared__ __align__(16) unsigned short Al[3][MROWS * 32];
    __shared__ __align__(16) unsigned short Bl[3][NF * 32 * 32];
    const int bm   = blockIdx.x * MROWS;
    const int bn   = blockIdx.y * (NF * 32);
    const int tid  = (int)threadIdx.x;
    const int wave = tid >> 6;
    const int lane = tid & 63;
    const int wr   = wave >> 1;
    const int wc   = wave & 1;
    const int q    = lane & 15;
    const int g    = lane >> 4;
    const int g4   = g * 4;
    const int rswz = (g ^ ((q >> 1) & 3)) << 3;   // physical slot offset (elems)

    f32x4 acc[MI][NF] = {};

    const int srow = lane >> 2;                               // row in 16-row chunk
    const int scol = ((lane & 3) ^ ((lane >> 3) & 3)) << 3;   // src col (elems)

    auto stage = [&](int buf, int k0) {
#pragma unroll
        for (int i = 0; i < AC; ++i) {
            const int chunk = wave * AC + i;
            GLOAD16(A + (size_t)(bm + chunk * 16 + srow) * K + (k0 + scol),
                    &Al[buf][chunk * 512]);
        }
#pragma unroll
        for (int i = 0; i < BC; ++i) {
            const int chunk = wave * BC + i;
            GLOAD16(B + (size_t)(bn + chunk * 16 + srow) * K + (k0 + scol),
                    &Bl[buf][chunk * 512]);
        }
    };

    stage(0, 0);
    stage(1, 32);

    const int nt = K / 32;               // 24
    for (int t = 0; t < nt; ++t) {
        const int cur = t % 3;
        // tile t resident (own loads) + cross-wave visibility via barrier
        if (t < nt - 1) {
            if constexpr (NL == 4)
                asm volatile("s_waitcnt vmcnt(4)\n\ts_barrier" ::: "memory");
            else
                asm volatile("s_waitcnt vmcnt(2)\n\ts_barrier" ::: "memory");
        } else {
            asm volatile("s_waitcnt vmcnt(0)\n\ts_barrier" ::: "memory");
        }
        if (t + 2 < nt) stage((cur + 2) % 3, (t + 2) * 32);

        bf16x8 af[MI], bf[NF];
#pragma unroll
        for (int mi = 0; mi < MI; ++mi)
            af[mi] = *(const bf16x8*)&Al[cur][(wr * (MROWS / 2) + mi * 16 + q) * 32 + rswz];
#pragma unroll
        for (int ni = 0; ni < NF; ++ni)
            bf[ni] = *(const bf16x8*)&Bl[cur][(wc * 16 * NF + ni * 16 + q) * 32 + rswz];
#pragma unroll
        for (int mi = 0; mi < MI; ++mi)
#pragma unroll
            for (int ni = 0; ni < NF; ++ni)
                acc[mi][ni] = __builtin_amdgcn_mfma_f32_16x16x32_bf16(
                    af[mi], bf[ni], acc[mi][ni], 0, 0, 0);
    }

#pragma unroll
    for (int mi = 0; mi < MI; ++mi) {
        const int row0 = bm + wr * (MROWS / 2) + mi * 16 + g4;
        if constexpr (MODE == 1) {
#pragma unroll
            for (int ni = 0; ni < NF; ++ni) {
                const int col = bn + wc * 16 * NF + ni * 16 + q;
#pragma unroll
                for (int r = 0; r < 4; ++r)
                    Cf[(size_t)(row0 + r) * N + col] = acc[mi][ni][r] + bias[col];
            }
        } else {
            if (bn < 1536) {
#pragma unroll
                for (int ni = 0; ni < NF; ++ni) {
                    const int col = bn + wc * 16 * NF + ni * 16 + q;
#pragma unroll
                    for (int r = 0; r < 4; ++r)
                        Cb[(size_t)(row0 + r) * 1536 + col] = f2bf(acc[mi][ni][r]);
                }
            } else {
                const int bb  = row0 >> 11;
                const int np  = row0 & 2047;           // np % 4 == 0
                const int tt  = np >> 6;
                const int wv  = (np >> 4) & 3;
                const int gg  = (np >> 2) & 3;
#pragma unroll
                for (int ni = 0; ni < NF; ++ni) {
                    const int vcol = bn + wc * 16 * NF + ni * 16 + q - 1536;
                    const int hv = vcol >> 6, d = vcol & 63;
                    const size_t idx =
                        ((size_t)((bb * 12 + hv) * 32 + tt) * 4 + wv) * 1024
                        + gg * 256 + d * 4;
                    uint2 w;
                    w.x = pack_bf16x2(acc[mi][ni][0], acc[mi][ni][1]);
                    w.y = pack_bf16x2(acc[mi][ni][2], acc[mi][ni][3]);
                    *reinterpret_cast<uint2*>(&Vt[idx]) = w;   // coalesced
                }
            }
        }
    }
}

// --- fused flash attention: kv-split waves, wave-private LDS, 0 barriers ---
// (R12 structure verbatim — benched 49.7-49.9 us, 0 conflicts, no spills)
// qk: [B*N][1536] bf16 (Q pre-scaled); vT tiled [bhh][t][w][g][d][j]
// 1D grid 768, XCD-chunked: xcd = bid&7 owns bh in {3*xcd..3*xcd+2}.
__global__ __launch_bounds__(256, 3) void attn_fwd(
    const unsigned short* __restrict__ qk,
    const unsigned short* __restrict__ vT,
    const int* __restrict__ mask,
    unsigned short* __restrict__ out)
{
    const int NN = 2048, H = 12;
    const int bid = (int)blockIdx.x;
    const int bhh = (bid & 7) * 3 + ((bid >> 3) >> 5);   // 0..23
    const int qt  = (bid >> 3) & 31;
    const int b   = bhh / H, h = bhh % H;
    const int q0  = qt * 64;
    const int tid = (int)threadIdx.x, wave = tid >> 6, lane = tid & 63;
    const int g   = lane >> 4;
    const int q   = lane & 15;
    const int swz = (q & 7) << 3;

    // LDS: K 2x4096 | V 2x4096 | lbuf 256 f32  => 33792 B
    __shared__ __align__(16) unsigned short LDS[16896];
    unsigned short* Kl0 = LDS;           // [buf][kv 64][d 64]
    unsigned short* Vl0 = LDS + 8192;    // [buf][wave][g 4][d 64][j 4]

    // wave-local mask vote: all 2048 entries nonzero?
    bool allone;
    {
        const int* mrow = mask + b * NN + lane * 32;
        unsigned mv = 0xFFFFFFFFu;
#pragma unroll
        for (int i = 0; i < 8; ++i) {
            int4 m = *reinterpret_cast<const int4*>(mrow + i * 4);
            mv = min(mv, min(min((unsigned)m.x, (unsigned)m.y),
                             min((unsigned)m.z, (unsigned)m.w)));
        }
        allone = __all(mv != 0u);
    }

    // Q B-fragments for all 4 q-tiles: B[k=d=kk*32+g*8+j][col=q0+16qt+q]
    bf16x8 qf[2][4];
#pragma unroll
    for (int kk = 0; kk < 2; ++kk)
#pragma unroll
        for (int qtl = 0; qtl < 4; ++qtl)
            qf[kk][qtl] = *reinterpret_cast<const bf16x8*>(
                &qk[(size_t)(b * NN + q0 + 16 * qtl + q) * 1536 + h * 64 + kk * 32 + g * 8]);

    // K staging (own 16 kv rows; linear LDS dest, inverse-swizzled source col)
    const char* kg0 = (const char*)(qk + (size_t)(b * NN + wave * 16 + (lane >> 3)) * 1536
                                    + 768 + h * 64 + ((lane & 7) ^ (lane >> 3)) * 8);
    const char* kg1 = kg0 + (size_t)8 * 1536 * 2;
    // V staging: vT tiled layout — perfectly linear, lane*16B
    const unsigned short* vgp = vT + ((size_t)bhh * 32 * 4 + wave) * 1024 + lane * 8;

    auto stageK = [&](int buf) {
        GLOAD16(kg0, &Kl0[buf * 4096 + wave * 1024]);
        GLOAD16(kg1, &Kl0[buf * 4096 + wave * 1024 + 512]);
        kg0 += (size_t)64 * 1536 * 2;
        kg1 += (size_t)64 * 1536 * 2;
    };
    auto stageV = [&](int buf) {
        GLOAD16(vgp,       &Vl0[buf * 4096 + wave * 1024]);
        GLOAD16(vgp + 512, &Vl0[buf * 4096 + wave * 1024 + 512]);
        vgp += 4096;                     // next kv tile
    };

    f32x4 oacc[4][4] = {};          // [ct: d-tile][qtl: q-tile]
    float l[4] = {0.f, 0.f, 0.f, 0.f};

    stageK(0); stageV(0);           // 4 loads in flight (no barrier needed)

    int cur = 0;
    for (int it = 0; it < 32; ++it) {
        if (it < 31) { stageK(cur ^ 1); stageV(cur ^ 1); }

        // K(it) resident; V(it) + next iter's 4 stay in flight
        if (it < 31) asm volatile("s_waitcnt vmcnt(6)" ::: "memory");
        else         asm volatile("s_waitcnt vmcnt(2)" ::: "memory");

        // S^T[own 16 kv][64 q] = K_own * Q^T  (exp2 units; scale pre-folded)
        f32x4 s[4] = {};
        __builtin_amdgcn_s_setprio(1);
#pragma unroll
        for (int kk = 0; kk < 2; ++kk) {
            bf16x8 kf = *(const bf16x8*)&Kl0[cur * 4096 + (16 * wave + q) * 64
                                             + ((kk * 32 + g * 8) ^ swz)];
#pragma unroll
            for (int qtl = 0; qtl < 4; ++qtl)
                s[qtl] = __builtin_amdgcn_mfma_f32_16x16x32_bf16(kf, qf[kk][qtl], s[qtl], 0, 0, 0);
        }
        __builtin_amdgcn_s_setprio(0);

        if (!allone) {               // cold path: mask by absolute kv
            int4 mr = *reinterpret_cast<const int4*>(
                &mask[b * NN + it * 64 + 16 * wave + 4 * g]);
#pragma unroll
            for (int qtl = 0; qtl < 4; ++qtl) {
                if (mr.x == 0) s[qtl][0] = -INFINITY;
                if (mr.y == 0) s[qtl][1] = -INFINITY;
                if (mr.z == 0) s[qtl][2] = -INFINITY;
                if (mr.w == 0) s[qtl][3] = -INFINITY;
            }
        }

        // p = exp2(s); per-lane l partials (reduced at epilogue); pack to bf16
        bf16x4 pb[4];
#pragma unroll
        for (int qtl = 0; qtl < 4; ++qtl) {
            float p0 = __builtin_amdgcn_exp2f(s[qtl][0]);
            float p1 = __builtin_amdgcn_exp2f(s[qtl][1]);
            float p2 = __builtin_amdgcn_exp2f(s[qtl][2]);
            float p3 = __builtin_amdgcn_exp2f(s[qtl][3]);
            l[qtl] += (p0 + p1) + (p2 + p3);
            uint2 t;
            t.x = pack_bf16x2(p0, p1);
            t.y = pack_bf16x2(p2, p3);
            pb[qtl] = __builtin_bit_cast(bf16x4, t);
        }

        // V(it) resident; next iter's 4 remain in flight
        if (it < 31) asm volatile("s_waitcnt vmcnt(4)" ::: "memory");
        else         asm volatile("s_waitcnt vmcnt(0)" ::: "memory");

        // O^T[64 d][64 q] partial += V_own^T * P^T  (P in registers)
        __builtin_amdgcn_s_setprio(1);
#pragma unroll
        for (int ct = 0; ct < 4; ++ct) {
            // [g][d][j] layout: banks 2q,2q+1 -> conflict-free
            bf16x4 va = *(const bf16x4*)&Vl0[cur * 4096 + wave * 1024
                                             + g * 256 + (16 * ct + q) * 4];
#pragma unroll
            for (int qtl = 0; qtl < 4; ++qtl)
                oacc[ct][qtl] = mfma16(va, pb[qtl], oacc[ct][qtl]);
        }
        __builtin_amdgcn_s_setprio(0);

        cur ^= 1;
    }

    __syncthreads();   // all waves done with K/V LDS before epilogue overlay

    // ---- epilogue: reduce l (over g, then waves) and O (over waves) ----
#pragma unroll
    for (int qtl = 0; qtl < 4; ++qtl) {
        l[qtl] += __shfl_xor(l[qtl], 16);
        l[qtl] += __shfl_xor(l[qtl], 32);
    }
    float* lb = (float*)&LDS[16384];
    float* fb = (float*)&LDS[0];
    if (g == 0) {
#pragma unroll
        for (int qtl = 0; qtl < 4; ++qtl) lb[wave * 64 + qtl * 16 + q] = l[qtl];
    }
    // round 1: waves 1,3 dump partials (16 KB each)
    if (wave & 1) {
        float* dst = fb + (wave >> 1) * 4096;
#pragma unroll
        for (int ct = 0; ct < 4; ++ct)
#pragma unroll
            for (int qtl = 0; qtl < 4; ++qtl)
                *reinterpret_cast<f32x4*>(&dst[(ct * 4 + qtl) * 256 + lane * 4]) = oacc[ct][qtl];
    }
    __syncthreads();
    if (!(wave & 1)) {
        float* srcp = fb + (wave >> 1) * 4096;
#pragma unroll
        for (int ct = 0; ct < 4; ++ct)
#pragma unroll
            for (int qtl = 0; qtl < 4; ++qtl)
                oacc[ct][qtl] += *reinterpret_cast<f32x4*>(&srcp[(ct * 4 + qtl) * 256 + lane * 4]);
    }
    __syncthreads();
    // round 2: wave 2 dumps merged partial
    if (wave == 2) {
#pragma unroll
        for (int ct = 0; ct < 4; ++ct)
#pragma unroll
            for (int qtl = 0; qtl < 4; ++qtl)
                *reinterpret_cast<f32x4*>(&fb[(ct * 4 + qtl) * 256 + lane * 4]) = oacc[ct][qtl];
    }
    __syncthreads();
    if (wave == 0) {
        float inv[4];
#pragma unroll
        for (int qtl = 0; qtl < 4; ++qtl)
            inv[qtl] = 1.0f / (lb[qtl * 16 + q] + lb[64 + qtl * 16 + q]
                              + lb[128 + qtl * 16 + q] + lb[192 + qtl * 16 + q]);
#pragma unroll
        for (int ct = 0; ct < 4; ++ct)
#pragma unroll
            for (int qtl = 0; qtl < 4; ++qtl) {
                f32x4 o = oacc[ct][qtl]
                        + *reinterpret_cast<f32x4*>(&fb[(ct * 4 + qtl) * 256 + lane * 4]);
                uint2 ow;
                ow.x = pack_bf16x2(o[0] * inv[qtl], o[1] * inv[qtl]);
                ow.y = pack_bf16x2(o[2] * inv[qtl], o[3] * inv[qtl]);
                *reinterpret_cast<uint2*>(
                    &out[(size_t)(b * NN + q0 + 16 * qtl + q) * 768 + h * 64 + 16 * ct + 4 * g]) = ow;
            }
    }
}

// ---------------- host launch ----------------
extern "C" void kernel_launch(void* const* d_in, const int* in_sizes, int n_in,
                              void* d_out, int out_size, void* d_ws, size_t ws_size,
                              hipStream_t stream)
{
    const float* x      = (const float*)d_in[0];
    const int*   mask   = (const int*)d_in[1];
    const float* qkv_w  = (const float*)d_in[2];
    const float* proj_w = (const float*)d_in[3];
    const float* proj_b = (const float*)d_in[4];
    float* out = (float*)d_out;

    const int BN = 2 * 2048;
    const int C  = 768;
    const int C3 = 2304;

    char* w = (char*)d_ws;
    unsigned short* xb    = (unsigned short*)w; w += (size_t)BN * C    * 2;
    unsigned short* wqkv  = (unsigned short*)w; w += (size_t)C3 * C    * 2;
    unsigned short* wproj = (unsigned short*)w; w += (size_t)C  * C    * 2;
    unsigned short* qk    = (unsigned short*)w; w += (size_t)BN * 1536 * 2;
    unsigned short* vT    = (unsigned short*)w; w += (size_t)24 * 64 * 2048 * 2;
    unsigned short* ao    = (unsigned short*)w;

    // fused converts (Q weight rows pre-scaled by 0.125*log2e)
    {
        const int total = (BN * C + C3 * C + C * C) / 4;
        cvt_all<<<total / 256, 256, 0, stream>>>(x, qkv_w, proj_w, xb, wqkv, wproj);
    }

    // qkv GEMM with split epilogue: Q,K -> qk[.][1536]; V -> vT (tiled layout)
    gemm_bt<2, 128, 4><<<dim3(BN / 128, C3 / 128), 256, 0, stream>>>(
        xb, wqkv, qk, vT, nullptr, nullptr, BN, C3, C);

    attn_fwd<<<dim3(768), 256, 0, stream>>>(qk, vT, mask, ao);

    // out = ao @ proj_w^T + b (fp32), 64x64 tiles -> 768 blocks (3/CU balanced)
    gemm_bt<1, 64, 2><<<dim3(BN / 64, C / 64), 256, 0, stream>>>(
        ao, wproj, nullptr, nullptr, out, proj_b, BN, C, C);
}